// Round 10
// baseline (534.456 us; speedup 1.0000x reference)
//
#include <hip/hip_runtime.h>
#include <hip/hip_bf16.h>
#include <math.h>

// Problem constants
#define NROWS 131072      // 32*64*64
#define DDIM  64
#define KCODE 1024
#define TAU_B 0.008f      // split-bf16 dist err <= ~2e-3; 4x margin

// d_out layout (float elements, return order)
#define OFF_Q    0L
#define OFF_LOSS 8388608L
#define OFF_PERP 8388609L
#define OFF_ENC  8388610L                 // only 8B-aligned (base ≡ 2 mod 4 floats)
#define OFF_IDX  (OFF_ENC + 134217728L)   // 142606338
#define OFF_DIST (OFF_IDX + 131072L)      // 142737410 — only 8B-aligned

// ws layout (float elements)
#define WS_ENORM 0L          // 1024 f
#define WS_ET    1024L       // 65536 f   eT[k][d]
#define WS_EBPH  66560L      // 32768 f = 65536 ushort (packed B hi)
#define WS_EBPL  99328L      // 32768 f
#define WS_IDX   132096L     // 131072 int (argmin indices kA -> kC)
#define WS_CNT   263168L     // 1024 int
#define WS_PART  395268L     // 8192 f

typedef short bf16x8 __attribute__((ext_vector_type(8)));
typedef float f32x4  __attribute__((ext_vector_type(4)));
typedef float f32x2  __attribute__((ext_vector_type(2)));
typedef _Float16 f16x4v __attribute__((ext_vector_type(4)));

__device__ inline unsigned short f2bf(float f) {
    unsigned u = __float_as_uint(f);
    unsigned r = (u + 0x7fffu + ((u >> 16) & 1u)) >> 16;
    return (unsigned short)r;
}
__device__ inline float bf2f(unsigned short h) {
    return __uint_as_float(((unsigned)h) << 16);
}
// f16 dist-tile swizzle: XOR bits 3,4 by row-group (i>>12 = row>>2).
// Preserves 8B (4 x f16) contiguity and alignment.
__device__ inline int dswz16(int i) { return i ^ (((i >> 12) & 3) << 3); }

// ---------------- k1a: e-norms (f32), eT for gather, zero cnt ----------------
__global__ __launch_bounds__(256) void k1a_prep(const float* __restrict__ e,
                                                float* __restrict__ enorm,
                                                float* __restrict__ eT,
                                                int* __restrict__ cnt) {
    int k = blockIdx.x * 256 + threadIdx.x;   // grid=4 -> k in [0,1024)
    float s = 0.f;
    #pragma unroll 8
    for (int d = 0; d < DDIM; ++d) {
        float v = e[(size_t)d * KCODE + k];
        s = fmaf(v, v, s);
        eT[(size_t)k * DDIM + d] = v;
    }
    enorm[k] = s;
    cnt[k] = 0;
}

// ---------------- k1b: pack e into MFMA-B fragment layout, hi/lo bf16 ----------------
__global__ __launch_bounds__(128) void k1b_pack(const float* __restrict__ e,
                                                unsigned short* __restrict__ ebph,
                                                unsigned short* __restrict__ ebpl) {
    const int gct = blockIdx.x;          // 0..63
    const int ks  = threadIdx.x >> 6;    // 0..1
    const int l   = threadIdx.x & 63;
    const int col = (gct << 4) | (l & 15);
    const int kb  = (ks << 5) + ((l >> 4) << 3);
    const size_t ob = ((size_t)((gct << 1) | ks) * 64 + l) * 8;
    #pragma unroll
    for (int j = 0; j < 8; ++j) {
        float f = e[(size_t)(kb + j) * KCODE + col];
        unsigned short h = f2bf(f);
        float lo = f - bf2f(h);
        ebph[ob + j] = h;
        ebpl[ob + j] = f2bf(lo);
    }
}

// ---------------- kA: MFMA dist + argmin + refine + idx + hist + loss partial ----------
// (byte-identical to round 7/9 — kept fixed; launched TWICE this round for
// differential timing: T10 - T9 = kA duration)
__global__ __launch_bounds__(256, 4) void kA_dist(const float* __restrict__ x,
                                                  const float* __restrict__ e,
                                                  const unsigned short* __restrict__ ebph,
                                                  const unsigned short* __restrict__ ebpl,
                                                  const float* __restrict__ enorm,
                                                  float* __restrict__ dist,
                                                  int* __restrict__ idxarr,
                                                  int* __restrict__ cnt,
                                                  float* __restrict__ partials) {
    __shared__ __align__(16) _Float16 dtH[16384];  // dist tile (f16), flat-2, swizzled
    __shared__ float hd[2];                        // flat 0,1 (row0 col0,1)
    __shared__ short xh[16 * 64];
    __shared__ short xl[16 * 64];
    __shared__ float xn[16];
    __shared__ float wm1[4][16], wm2[4][16];
    __shared__ int   wi1[4][16];
    __shared__ float ps[16];
    __shared__ int   sidx[16];
    __shared__ int   nearmask;
    __shared__ float xsh[DDIM];
    __shared__ double wbv[4];
    __shared__ int    wbi[4];

    const int tid  = threadIdx.x;
    const int lane = tid & 63;
    const int w    = tid >> 6;
    const int rowbase = blockIdx.x * 16;

    // ---- stage x tile: f32 -> (hi,lo) bf16 in LDS; row norms via shuffle
    {
        if (tid == 0) nearmask = 0;
        float4 v = ((const float4*)(x + (size_t)rowbase * DDIM))[tid];
        int fi = tid * 4, r = fi >> 6, c = fi & 63;
        float fv[4] = {v.x, v.y, v.z, v.w};
        short hv[4], lv[4];
        #pragma unroll
        for (int q = 0; q < 4; ++q) {
            unsigned short hh = f2bf(fv[q]);
            hv[q] = (short)hh;
            lv[q] = (short)f2bf(fv[q] - bf2f(hh));
        }
        *(short4*)&xh[r * 64 + c] = make_short4(hv[0], hv[1], hv[2], hv[3]);
        *(short4*)&xl[r * 64 + c] = make_short4(lv[0], lv[1], lv[2], lv[3]);
        float s4 = fmaf(v.x, v.x, fmaf(v.y, v.y, fmaf(v.z, v.z, v.w * v.w)));
        #pragma unroll
        for (int m = 1; m < 16; m <<= 1) s4 += __shfl_xor(s4, m);
        if ((lane & 15) == 0) xn[r] = s4;   // r == tid>>4 for the 16 lanes of a row
    }
    __syncthreads();

    // ---- A fragments: lane l -> row=l&15, k=(l>>4)*8+j (+32 for second K-step)
    const int arow = lane & 15, akb = (lane >> 4) << 3;
    bf16x8 ah0 = *(const bf16x8*)&xh[arow * 64 + akb];
    bf16x8 ah1 = *(const bf16x8*)&xh[arow * 64 + 32 + akb];
    bf16x8 al0 = *(const bf16x8*)&xl[arow * 64 + akb];
    bf16x8 al1 = *(const bf16x8*)&xl[arow * 64 + 32 + akb];

    const int wr   = (lane >> 4) << 2;       // C-fragment row block (rows wr..wr+3)
    const int colb = (w << 8) | (lane & 15); // this lane's column (per ct: + ct*16)
    float xnv[4];
    #pragma unroll
    for (int r = 0; r < 4; ++r) xnv[r] = xn[wr + r];
    float env[16];
    #pragma unroll
    for (int ct = 0; ct < 16; ++ct) env[ct] = enorm[colb + (ct << 4)];  // L2-hot

    float m1[4], m2[4];
    int   i1[4];
    #pragma unroll
    for (int r = 0; r < 4; ++r) { m1[r] = 3.4e38f; m2[r] = 3.4e38f; i1[r] = 1 << 30; }

    #pragma unroll 4
    for (int ct = 0; ct < 16; ++ct) {
        const int gct = (w << 4) | ct;
        const size_t bo = ((size_t)(gct << 1) * 64 + lane) * 8;
        bf16x8 bh0 = *(const bf16x8*)(ebph + bo);
        bf16x8 bh1 = *(const bf16x8*)(ebph + bo + 512);
        bf16x8 bl0 = *(const bf16x8*)(ebpl + bo);
        bf16x8 bl1 = *(const bf16x8*)(ebpl + bo + 512);

        f32x4 d = {0.f, 0.f, 0.f, 0.f};
        d = __builtin_amdgcn_mfma_f32_16x16x32_bf16(ah0, bh0, d, 0, 0, 0);
        d = __builtin_amdgcn_mfma_f32_16x16x32_bf16(ah1, bh1, d, 0, 0, 0);
        d = __builtin_amdgcn_mfma_f32_16x16x32_bf16(ah0, bl0, d, 0, 0, 0);
        d = __builtin_amdgcn_mfma_f32_16x16x32_bf16(ah1, bl1, d, 0, 0, 0);
        d = __builtin_amdgcn_mfma_f32_16x16x32_bf16(al0, bh0, d, 0, 0, 0);
        d = __builtin_amdgcn_mfma_f32_16x16x32_bf16(al1, bh1, d, 0, 0, 0);

        const int col = colb + (ct << 4);
        #pragma unroll
        for (int r = 0; r < 4; ++r) {
            float o = fmaf(-2.f, d[r], xnv[r] + env[ct]);
            if (o < m1[r]) { m2[r] = m1[r]; m1[r] = o; i1[r] = col; }
            else if (o < m2[r]) m2[r] = o;
            const int fl = ((wr + r) << 10) + col;
            if (fl >= 2) dtH[dswz16(fl - 2)] = (_Float16)o;
            else         hd[fl] = o;
        }
    }

    // ---- merge across the 16 lanes sharing each row group, tie -> lower index
    #pragma unroll
    for (int m = 1; m < 16; m <<= 1) {
        #pragma unroll
        for (int r = 0; r < 4; ++r) {
            float om1 = __shfl_xor(m1[r], m);
            int   oi1 = __shfl_xor(i1[r], m);
            float om2 = __shfl_xor(m2[r], m);
            if (om1 < m1[r] || (om1 == m1[r] && oi1 < i1[r])) {
                m2[r] = fminf(m1[r], om2); m1[r] = om1; i1[r] = oi1;
            } else {
                m2[r] = fminf(m2[r], om1);
            }
        }
    }
    if ((lane & 15) == 0) {
        #pragma unroll
        for (int r = 0; r < 4; ++r) {
            wm1[w][wr + r] = m1[r];
            wm2[w][wr + r] = m2[r];
            wi1[w][wr + r] = i1[r];
        }
    }
    __syncthreads();
    if (tid < 16) {
        float bm1 = wm1[0][tid], bm2 = wm2[0][tid];
        int   bi  = wi1[0][tid];
        #pragma unroll
        for (int wv = 1; wv < 4; ++wv) {
            float om1 = wm1[wv][tid], om2 = wm2[wv][tid];
            int   oi  = wi1[wv][tid];
            if (om1 < bm1 || (om1 == bm1 && oi < bi)) {
                bm2 = fminf(bm1, om2); bm1 = om1; bi = oi;
            } else {
                bm2 = fminf(bm2, om1);
            }
        }
        sidx[tid] = bi;
        ps[tid]   = bm1;                    // min-dist == ||x-q||^2 for loss
        if (bm2 - bm1 < TAU_B) atomicOr(&nearmask, 1 << tid);
    }
    __syncthreads();

    // ---- dist sweep: flat contiguous f32x4 stores (fill-identical pattern)
    {
        float* dbase = dist + ((size_t)rowbase << 10);   // ≡ 2 mod 4 floats
        #pragma unroll
        for (int j = 0; j < 16; ++j) {
            const int s = (j << 8) + tid;                // 0..4095
            if (s < 4095) {
                const int i0 = s << 2;
                const int iw = dswz16(i0);
                f16x4v h = *(const f16x4v*)&dtH[iw];
                f32x4 v = {(float)h[0], (float)h[1], (float)h[2], (float)h[3]};
                *(f32x4*)(dbase + 2 + i0) = v;
            }
        }
        if (tid == 255) {
            const int it = dswz16(16380);
            *(f32x2*)(dbase)         = (f32x2){hd[0], hd[1]};
            *(f32x2*)(dbase + 16382) = (f32x2){(float)dtH[it], (float)dtH[it + 1]};
        }
    }

    // ---- inline f64 refinement of near-tie rows (rare)
    if (nearmask) {
        for (int mrow = nearmask; mrow; mrow &= (mrow - 1)) {
            const int r = __ffs(mrow) - 1;
            if (tid < DDIM) xsh[tid] = x[(size_t)(rowbase + r) * DDIM + tid];
            __syncthreads();
            const int k0 = tid * 4;
            double dd[4] = {0.0, 0.0, 0.0, 0.0};
            for (int d = 0; d < DDIM; ++d) {
                double xd = (double)xsh[d];
                float4 ev = *(const float4*)(e + (size_t)d * KCODE + k0);
                double t0 = xd - (double)ev.x; dd[0] = fma(t0, t0, dd[0]);
                double t1 = xd - (double)ev.y; dd[1] = fma(t1, t1, dd[1]);
                double t2 = xd - (double)ev.z; dd[2] = fma(t2, t2, dd[2]);
                double t3 = xd - (double)ev.w; dd[3] = fma(t3, t3, dd[3]);
            }
            double best = dd[0]; int bidx = k0;
            #pragma unroll
            for (int c = 1; c < 4; ++c)
                if (dd[c] < best) { best = dd[c]; bidx = k0 + c; }
            #pragma unroll
            for (int m = 1; m < 64; m <<= 1) {
                double ob = __shfl_xor(best, m);
                int    oi = __shfl_xor(bidx, m);
                if (ob < best || (ob == best && oi < bidx)) { best = ob; bidx = oi; }
            }
            if (lane == 0) { wbv[w] = best; wbi[w] = bidx; }
            __syncthreads();
            if (tid == 0) {
                double bb = wbv[0]; int bi = wbi[0];
                #pragma unroll
                for (int wv = 1; wv < 4; ++wv)
                    if (wbv[wv] < bb || (wbv[wv] == bb && wbi[wv] < bi)) {
                        bb = wbv[wv]; bi = wbi[wv];
                    }
                sidx[r] = bi; ps[r] = (float)bb;
            }
            __syncthreads();
        }
    }

    // ---- indices + histogram + loss partial
    if (tid < 16) {
        const int idx = sidx[tid];
        idxarr[rowbase + tid] = idx;
        atomicAdd(cnt + idx, 1);
    }
    if (tid == 64) {
        float s = 0.f;
        #pragma unroll
        for (int j = 0; j < 16; ++j) s += ps[j];
        partials[blockIdx.x] = s;
    }
}

// ---------------- kC: enc as PURE zero-stream + one-hot fixup; outq; indices -------
__global__ __launch_bounds__(256) void kC_final(const float* __restrict__ eT,
                                                const int* __restrict__ idxarr,
                                                float* __restrict__ outq,
                                                float* __restrict__ enc,
                                                float* __restrict__ outidx) {
    __shared__ int sidx[64];
    const int tid = threadIdx.x;
    const int rowbase = blockIdx.x * 64;

    if (tid < 64) {
        const int grow = rowbase + tid;
        const int idx = idxarr[grow];
        sidx[tid] = idx;
        outidx[grow] = (float)idx;
    }

    // outq: gather codebook rows, f32x4 lanes (16 lanes/row)
    #pragma unroll
    for (int it = 0; it < 4; ++it) {
        const int row = (it << 4) + (tid >> 4);
        const int grow = rowbase + row;
        const int idx = idxarr[grow];
        f32x4 ev = *(const f32x4*)(eT + (size_t)idx * DDIM + ((tid & 15) << 2));
        *((f32x4*)(outq + ((size_t)grow << 6)) + (tid & 15)) = ev;
    }

    // enc: 256KB contiguous zero stream, base ≡ 2 mod 4 floats.
    float* ebase = enc + ((size_t)rowbase << 10);
    const f32x4 z4 = {0.f, 0.f, 0.f, 0.f};
    #pragma unroll 9
    for (int j = 0; j < 63; ++j) {
        const int s = (j << 8) + tid;          // 0..16127
        *(f32x4*)(ebase + 2 + (s << 2)) = z4;
    }
    if (tid < 255) {
        const int s = (63 << 8) + tid;         // 16128..16382
        *(f32x4*)(ebase + 2 + (s << 2)) = z4;
    }
    if (tid == 255) {
        *(f32x2*)(ebase)         = (f32x2){0.f, 0.f};
        *(f32x2*)(ebase + 65534) = (f32x2){0.f, 0.f};
    }

    // drain zero-stores, then fixup one-hot 1.0s
    __syncthreads();
    if (tid < 64) {
        ebase[((size_t)tid << 10) + sidx[tid]] = 1.0f;
    }
}

// ---------------- k6: loss + perplexity ----------------
__global__ __launch_bounds__(256) void k6_scalar(const float* __restrict__ partials,
                                                 const int* __restrict__ cnt,
                                                 float* __restrict__ outloss,
                                                 float* __restrict__ outperp) {
    __shared__ double sd[256];
    const int tid = threadIdx.x;
    double s = 0.0;
    for (int i = tid; i < 8192; i += 256) s += (double)partials[i];
    sd[tid] = s;
    __syncthreads();
    for (int st = 128; st > 0; st >>= 1) {
        if (tid < st) sd[tid] += sd[tid + st];
        __syncthreads();
    }
    const double total = sd[0];
    __syncthreads();
    double h = 0.0;
    for (int k = tid; k < KCODE; k += 256) {
        double p = (double)cnt[k] / (double)NROWS;
        h -= p * log(p + 1e-10);
    }
    sd[tid] = h;
    __syncthreads();
    for (int st = 128; st > 0; st >>= 1) {
        if (tid < st) sd[tid] += sd[tid + st];
        __syncthreads();
    }
    if (tid == 0) {
        *outloss = (float)(total * 1.25 / (double)((long)NROWS * DDIM));
        *outperp = (float)exp(sd[0]);
    }
}

extern "C" void kernel_launch(void* const* d_in, const int* in_sizes, int n_in,
                              void* d_out, int out_size, void* d_ws, size_t ws_size,
                              hipStream_t stream) {
    const float* x = (const float*)d_in[0];       // [131072, 64]
    const float* e = (const float*)d_in[1];       // [64, 1024]
    float* out = (float*)d_out;

    float* ws_f = (float*)d_ws;
    float* enorm   = ws_f + WS_ENORM;
    float* eT      = ws_f + WS_ET;
    unsigned short* ebph = (unsigned short*)(ws_f + WS_EBPH);
    unsigned short* ebpl = (unsigned short*)(ws_f + WS_EBPL);
    int*   idxarr  = (int*)(ws_f + WS_IDX);
    int*   cnt     = (int*)(ws_f + WS_CNT);
    float* partials= ws_f + WS_PART;

    float* outq    = out + OFF_Q;
    float* outloss = out + OFF_LOSS;
    float* outperp = out + OFF_PERP;
    float* enc     = out + OFF_ENC;
    float* outidx  = out + OFF_IDX;
    float* dist    = out + OFF_DIST;

    hipLaunchKernelGGL(k1a_prep, dim3(4),    dim3(256), 0, stream, e, enorm, eT, cnt);
    hipLaunchKernelGGL(k1b_pack, dim3(64),   dim3(128), 0, stream, e, ebph, ebpl);
    // kA launch #1 (measurement copy): identical work, deterministic outputs
    hipLaunchKernelGGL(kA_dist,  dim3(8192), dim3(256), 0, stream, x, e, ebph, ebpl, enorm,
                       dist, idxarr, cnt, partials);
    // re-zero cnt, then kA launch #2 (the "real" one) — T10 - T9 == one kA duration
    hipLaunchKernelGGL(k1a_prep, dim3(4),    dim3(256), 0, stream, e, enorm, eT, cnt);
    hipLaunchKernelGGL(kA_dist,  dim3(8192), dim3(256), 0, stream, x, e, ebph, ebpl, enorm,
                       dist, idxarr, cnt, partials);
    hipLaunchKernelGGL(kC_final, dim3(2048), dim3(256), 0, stream, eT, idxarr, outq, enc, outidx);
    hipLaunchKernelGGL(k6_scalar,dim3(1),    dim3(256), 0, stream, partials, cnt, outloss, outperp);
}

// Round 11
// 283.314 us; speedup vs baseline: 1.8864x; 1.8864x over previous
//
#include <hip/hip_runtime.h>
#include <hip/hip_bf16.h>
#include <math.h>

// Problem constants
#define NROWS 131072      // 32*64*64
#define DDIM  64
#define KCODE 1024
#define TAU_B 0.008f      // split-bf16 dist err <= ~2e-3; 4x margin

// d_out layout (float elements, return order)
#define OFF_Q    0L
#define OFF_LOSS 8388608L
#define OFF_PERP 8388609L
#define OFF_ENC  8388610L                 // only 8B-aligned (base ≡ 2 mod 4 floats)
#define OFF_IDX  (OFF_ENC + 134217728L)   // 142606338
#define OFF_DIST (OFF_IDX + 131072L)      // 142737410 — only 8B-aligned

// ws layout (float elements)
#define WS_ENORM 0L          // 1024 f
#define WS_ET    1024L       // 65536 f   eT[k][d]
#define WS_EBPH  66560L      // 32768 f = 65536 ushort (packed B hi)
#define WS_EBPL  99328L      // 32768 f
#define WS_CNT   263168L     // 1024 int
#define WS_PART  395268L     // 8192 f

typedef short bf16x8 __attribute__((ext_vector_type(8)));
typedef float f32x4  __attribute__((ext_vector_type(4)));
typedef float f32x2  __attribute__((ext_vector_type(2)));
typedef _Float16 f16x4v __attribute__((ext_vector_type(4)));

__device__ inline unsigned short f2bf(float f) {
    unsigned u = __float_as_uint(f);
    unsigned r = (u + 0x7fffu + ((u >> 16) & 1u)) >> 16;
    return (unsigned short)r;
}
__device__ inline float bf2f(unsigned short h) {
    return __uint_as_float(((unsigned)h) << 16);
}
// f16 dist-tile swizzle: XOR bits 3,4 by row-group (i>>12 = row>>2).
// Preserves 8B (4 x f16) contiguity and alignment.
__device__ inline int dswz16(int i) { return i ^ (((i >> 12) & 3) << 3); }

// ---------------- k1a: e-norms (f32), eT for gather, zero cnt ----------------
__global__ __launch_bounds__(256) void k1a_prep(const float* __restrict__ e,
                                                float* __restrict__ enorm,
                                                float* __restrict__ eT,
                                                int* __restrict__ cnt) {
    int k = blockIdx.x * 256 + threadIdx.x;   // grid=4 -> k in [0,1024)
    float s = 0.f;
    #pragma unroll 8
    for (int d = 0; d < DDIM; ++d) {
        float v = e[(size_t)d * KCODE + k];
        s = fmaf(v, v, s);
        eT[(size_t)k * DDIM + d] = v;
    }
    enorm[k] = s;
    cnt[k] = 0;
}

// ---------------- k1b: pack e into MFMA-B fragment layout, hi/lo bf16 ----------------
__global__ __launch_bounds__(128) void k1b_pack(const float* __restrict__ e,
                                                unsigned short* __restrict__ ebph,
                                                unsigned short* __restrict__ ebpl) {
    const int gct = blockIdx.x;          // 0..63
    const int ks  = threadIdx.x >> 6;    // 0..1
    const int l   = threadIdx.x & 63;
    const int col = (gct << 4) | (l & 15);
    const int kb  = (ks << 5) + ((l >> 4) << 3);
    const size_t ob = ((size_t)((gct << 1) | ks) * 64 + l) * 8;
    #pragma unroll
    for (int j = 0; j < 8; ++j) {
        float f = e[(size_t)(kb + j) * KCODE + col];
        unsigned short h = f2bf(f);
        float lo = f - bf2f(h);
        ebph[ob + j] = h;
        ebpl[ob + j] = f2bf(lo);
    }
}

// ---------------- kA: fused dist + enc(zero-stream interleaved in MFMA loop) ----------
// + argmin + refine + one-hot fixup + outq + idx + hist + loss partial.
// The 64KB/block of enc zeros is data-independent: streamed DURING the MFMA
// phase so the HBM write pipe is busy while compute runs. Fixup after refine
// (barriers have drained vmcnt by then).
__global__ __launch_bounds__(256, 4) void kA_fused(const float* __restrict__ x,
                                                   const float* __restrict__ e,
                                                   const unsigned short* __restrict__ ebph,
                                                   const unsigned short* __restrict__ ebpl,
                                                   const float* __restrict__ enorm,
                                                   const float* __restrict__ eT,
                                                   float* __restrict__ dist,
                                                   float* __restrict__ enc,
                                                   float* __restrict__ outq,
                                                   float* __restrict__ outidx,
                                                   int* __restrict__ cnt,
                                                   float* __restrict__ partials) {
    __shared__ __align__(16) _Float16 dtH[16384];  // dist tile (f16), flat-2, swizzled
    __shared__ float hd[2];                        // flat 0,1 (row0 col0,1)
    __shared__ short xh[16 * 64];
    __shared__ short xl[16 * 64];
    __shared__ float xn[16];
    __shared__ float wm1[4][16], wm2[4][16];
    __shared__ int   wi1[4][16];
    __shared__ float ps[16];
    __shared__ int   sidx[16];
    __shared__ int   nearmask;
    __shared__ float xsh[DDIM];
    __shared__ double wbv[4];
    __shared__ int    wbi[4];

    const int tid  = threadIdx.x;
    const int lane = tid & 63;
    const int w    = tid >> 6;
    const int rowbase = blockIdx.x * 16;
    float* ebase = enc + ((size_t)blockIdx.x << 14);   // 16 rows x 1024, ≡2 mod 4

    // ---- stage x tile: f32 -> (hi,lo) bf16 in LDS; row norms via shuffle
    {
        if (tid == 0) nearmask = 0;
        float4 v = ((const float4*)(x + (size_t)rowbase * DDIM))[tid];
        int fi = tid * 4, r = fi >> 6, c = fi & 63;
        float fv[4] = {v.x, v.y, v.z, v.w};
        short hv[4], lv[4];
        #pragma unroll
        for (int q = 0; q < 4; ++q) {
            unsigned short hh = f2bf(fv[q]);
            hv[q] = (short)hh;
            lv[q] = (short)f2bf(fv[q] - bf2f(hh));
        }
        *(short4*)&xh[r * 64 + c] = make_short4(hv[0], hv[1], hv[2], hv[3]);
        *(short4*)&xl[r * 64 + c] = make_short4(lv[0], lv[1], lv[2], lv[3]);
        float s4 = fmaf(v.x, v.x, fmaf(v.y, v.y, fmaf(v.z, v.z, v.w * v.w)));
        #pragma unroll
        for (int m = 1; m < 16; m <<= 1) s4 += __shfl_xor(s4, m);
        if ((lane & 15) == 0) xn[r] = s4;   // r == tid>>4 for the 16 lanes of a row
    }
    __syncthreads();

    // ---- A fragments: lane l -> row=l&15, k=(l>>4)*8+j (+32 for second K-step)
    const int arow = lane & 15, akb = (lane >> 4) << 3;
    bf16x8 ah0 = *(const bf16x8*)&xh[arow * 64 + akb];
    bf16x8 ah1 = *(const bf16x8*)&xh[arow * 64 + 32 + akb];
    bf16x8 al0 = *(const bf16x8*)&xl[arow * 64 + akb];
    bf16x8 al1 = *(const bf16x8*)&xl[arow * 64 + 32 + akb];

    const int wr   = (lane >> 4) << 2;       // C-fragment row block (rows wr..wr+3)
    const int colb = (w << 8) | (lane & 15); // this lane's column (per ct: + ct*16)
    float xnv[4];
    #pragma unroll
    for (int r = 0; r < 4; ++r) xnv[r] = xn[wr + r];
    float env[16];
    #pragma unroll
    for (int ct = 0; ct < 16; ++ct) env[ct] = enorm[colb + (ct << 4)];  // L2-hot

    float m1[4], m2[4];
    int   i1[4];
    #pragma unroll
    for (int r = 0; r < 4; ++r) { m1[r] = 3.4e38f; m2[r] = 3.4e38f; i1[r] = 1 << 30; }

    const f32x4 z4 = {0.f, 0.f, 0.f, 0.f};

    #pragma unroll 4
    for (int ct = 0; ct < 16; ++ct) {
        const int gct = (w << 4) | ct;
        const size_t bo = ((size_t)(gct << 1) * 64 + lane) * 8;
        bf16x8 bh0 = *(const bf16x8*)(ebph + bo);
        bf16x8 bh1 = *(const bf16x8*)(ebph + bo + 512);
        bf16x8 bl0 = *(const bf16x8*)(ebpl + bo);
        bf16x8 bl1 = *(const bf16x8*)(ebpl + bo + 512);

        // interleaved enc zero-stream: one f32x4 per thread per ct (64KB/block total)
        {
            const int s = (ct << 8) + tid;          // 0..4095
            if (s < 4095) {
                *(f32x4*)(ebase + 2 + (s << 2)) = z4;
            } else {                                 // s == 4095: head + tail f32x2
                *(f32x2*)(ebase)         = (f32x2){0.f, 0.f};
                *(f32x2*)(ebase + 16382) = (f32x2){0.f, 0.f};
            }
        }

        f32x4 d = {0.f, 0.f, 0.f, 0.f};
        d = __builtin_amdgcn_mfma_f32_16x16x32_bf16(ah0, bh0, d, 0, 0, 0);
        d = __builtin_amdgcn_mfma_f32_16x16x32_bf16(ah1, bh1, d, 0, 0, 0);
        d = __builtin_amdgcn_mfma_f32_16x16x32_bf16(ah0, bl0, d, 0, 0, 0);
        d = __builtin_amdgcn_mfma_f32_16x16x32_bf16(ah1, bl1, d, 0, 0, 0);
        d = __builtin_amdgcn_mfma_f32_16x16x32_bf16(al0, bh0, d, 0, 0, 0);
        d = __builtin_amdgcn_mfma_f32_16x16x32_bf16(al1, bh1, d, 0, 0, 0);

        const int col = colb + (ct << 4);
        #pragma unroll
        for (int r = 0; r < 4; ++r) {
            float o = fmaf(-2.f, d[r], xnv[r] + env[ct]);
            if (o < m1[r]) { m2[r] = m1[r]; m1[r] = o; i1[r] = col; }
            else if (o < m2[r]) m2[r] = o;
            const int fl = ((wr + r) << 10) + col;
            if (fl >= 2) dtH[dswz16(fl - 2)] = (_Float16)o;
            else         hd[fl] = o;
        }
    }

    // ---- merge across the 16 lanes sharing each row group, tie -> lower index
    #pragma unroll
    for (int m = 1; m < 16; m <<= 1) {
        #pragma unroll
        for (int r = 0; r < 4; ++r) {
            float om1 = __shfl_xor(m1[r], m);
            int   oi1 = __shfl_xor(i1[r], m);
            float om2 = __shfl_xor(m2[r], m);
            if (om1 < m1[r] || (om1 == m1[r] && oi1 < i1[r])) {
                m2[r] = fminf(m1[r], om2); m1[r] = om1; i1[r] = oi1;
            } else {
                m2[r] = fminf(m2[r], om1);
            }
        }
    }
    if ((lane & 15) == 0) {
        #pragma unroll
        for (int r = 0; r < 4; ++r) {
            wm1[w][wr + r] = m1[r];
            wm2[w][wr + r] = m2[r];
            wi1[w][wr + r] = i1[r];
        }
    }
    __syncthreads();
    if (tid < 16) {
        float bm1 = wm1[0][tid], bm2 = wm2[0][tid];
        int   bi  = wi1[0][tid];
        #pragma unroll
        for (int wv = 1; wv < 4; ++wv) {
            float om1 = wm1[wv][tid], om2 = wm2[wv][tid];
            int   oi  = wi1[wv][tid];
            if (om1 < bm1 || (om1 == bm1 && oi < bi)) {
                bm2 = fminf(bm1, om2); bm1 = om1; bi = oi;
            } else {
                bm2 = fminf(bm2, om1);
            }
        }
        sidx[tid] = bi;
        ps[tid]   = bm1;                    // min-dist == ||x-q||^2 for loss
        if (bm2 - bm1 < TAU_B) atomicOr(&nearmask, 1 << tid);
    }
    __syncthreads();

    // ---- dist sweep: flat contiguous f32x4 stores (fill-identical pattern)
    {
        float* dbase = dist + ((size_t)rowbase << 10);   // ≡ 2 mod 4 floats
        #pragma unroll
        for (int j = 0; j < 16; ++j) {
            const int s = (j << 8) + tid;                // 0..4095
            if (s < 4095) {
                const int i0 = s << 2;
                const int iw = dswz16(i0);
                f16x4v h = *(const f16x4v*)&dtH[iw];
                f32x4 v = {(float)h[0], (float)h[1], (float)h[2], (float)h[3]};
                *(f32x4*)(dbase + 2 + i0) = v;
            }
        }
        if (tid == 255) {
            const int it = dswz16(16380);
            *(f32x2*)(dbase)         = (f32x2){hd[0], hd[1]};
            *(f32x2*)(dbase + 16382) = (f32x2){(float)dtH[it], (float)dtH[it + 1]};
        }
    }

    // ---- inline f64 refinement of near-tie rows (rare)
    if (nearmask) {
        for (int mrow = nearmask; mrow; mrow &= (mrow - 1)) {
            const int r = __ffs(mrow) - 1;
            if (tid < DDIM) xsh[tid] = x[(size_t)(rowbase + r) * DDIM + tid];
            __syncthreads();
            const int k0 = tid * 4;
            double dd[4] = {0.0, 0.0, 0.0, 0.0};
            for (int d = 0; d < DDIM; ++d) {
                double xd = (double)xsh[d];
                float4 ev = *(const float4*)(e + (size_t)d * KCODE + k0);
                double t0 = xd - (double)ev.x; dd[0] = fma(t0, t0, dd[0]);
                double t1 = xd - (double)ev.y; dd[1] = fma(t1, t1, dd[1]);
                double t2 = xd - (double)ev.z; dd[2] = fma(t2, t2, dd[2]);
                double t3 = xd - (double)ev.w; dd[3] = fma(t3, t3, dd[3]);
            }
            double best = dd[0]; int bidx = k0;
            #pragma unroll
            for (int c = 1; c < 4; ++c)
                if (dd[c] < best) { best = dd[c]; bidx = k0 + c; }
            #pragma unroll
            for (int m = 1; m < 64; m <<= 1) {
                double ob = __shfl_xor(best, m);
                int    oi = __shfl_xor(bidx, m);
                if (ob < best || (ob == best && oi < bidx)) { best = ob; bidx = oi; }
            }
            if (lane == 0) { wbv[w] = best; wbi[w] = bidx; }
            __syncthreads();
            if (tid == 0) {
                double bb = wbv[0]; int bi = wbi[0];
                #pragma unroll
                for (int wv = 1; wv < 4; ++wv)
                    if (wbv[wv] < bb || (wbv[wv] == bb && wbi[wv] < bi)) {
                        bb = wbv[wv]; bi = wbi[wv];
                    }
                sidx[r] = bi; ps[r] = (float)bb;
            }
            __syncthreads();
        }
    }

    // ---- epilogue: one-hot fixup (enc zeros drained at prior barriers),
    //      outq gather, indices, histogram, loss partial
    if (tid < 16) {
        const int idx = sidx[tid];
        ebase[((size_t)tid << 10) + idx] = 1.0f;
        outidx[rowbase + tid] = (float)idx;
        atomicAdd(cnt + idx, 1);
    }
    {
        const int r = tid >> 4, c = tid & 15;
        const int idx = sidx[r];
        f32x4 ev = *(const f32x4*)(eT + (size_t)idx * DDIM + (c << 2));
        *((f32x4*)(outq + ((size_t)(rowbase + r) << 6)) + c) = ev;
    }
    if (tid == 64) {
        float s = 0.f;
        #pragma unroll
        for (int j = 0; j < 16; ++j) s += ps[j];
        partials[blockIdx.x] = s;
    }
}

// ---------------- k6: loss + perplexity ----------------
__global__ __launch_bounds__(256) void k6_scalar(const float* __restrict__ partials,
                                                 const int* __restrict__ cnt,
                                                 float* __restrict__ outloss,
                                                 float* __restrict__ outperp) {
    __shared__ double sd[256];
    const int tid = threadIdx.x;
    double s = 0.0;
    for (int i = tid; i < 8192; i += 256) s += (double)partials[i];
    sd[tid] = s;
    __syncthreads();
    for (int st = 128; st > 0; st >>= 1) {
        if (tid < st) sd[tid] += sd[tid + st];
        __syncthreads();
    }
    const double total = sd[0];
    __syncthreads();
    double h = 0.0;
    for (int k = tid; k < KCODE; k += 256) {
        double p = (double)cnt[k] / (double)NROWS;
        h -= p * log(p + 1e-10);
    }
    sd[tid] = h;
    __syncthreads();
    for (int st = 128; st > 0; st >>= 1) {
        if (tid < st) sd[tid] += sd[tid + st];
        __syncthreads();
    }
    if (tid == 0) {
        *outloss = (float)(total * 1.25 / (double)((long)NROWS * DDIM));
        *outperp = (float)exp(sd[0]);
    }
}

extern "C" void kernel_launch(void* const* d_in, const int* in_sizes, int n_in,
                              void* d_out, int out_size, void* d_ws, size_t ws_size,
                              hipStream_t stream) {
    const float* x = (const float*)d_in[0];       // [131072, 64]
    const float* e = (const float*)d_in[1];       // [64, 1024]
    float* out = (float*)d_out;

    float* ws_f = (float*)d_ws;
    float* enorm   = ws_f + WS_ENORM;
    float* eT      = ws_f + WS_ET;
    unsigned short* ebph = (unsigned short*)(ws_f + WS_EBPH);
    unsigned short* ebpl = (unsigned short*)(ws_f + WS_EBPL);
    int*   cnt     = (int*)(ws_f + WS_CNT);
    float* partials= ws_f + WS_PART;

    float* outq    = out + OFF_Q;
    float* outloss = out + OFF_LOSS;
    float* outperp = out + OFF_PERP;
    float* enc     = out + OFF_ENC;
    float* outidx  = out + OFF_IDX;
    float* dist    = out + OFF_DIST;

    hipLaunchKernelGGL(k1a_prep, dim3(4),    dim3(256), 0, stream, e, enorm, eT, cnt);
    hipLaunchKernelGGL(k1b_pack, dim3(64),   dim3(128), 0, stream, e, ebph, ebpl);
    hipLaunchKernelGGL(kA_fused, dim3(8192), dim3(256), 0, stream, x, e, ebph, ebpl, enorm,
                       eT, dist, enc, outq, outidx, cnt, partials);
    hipLaunchKernelGGL(k6_scalar,dim3(1),    dim3(256), 0, stream, partials, cnt, outloss, outperp);
}